// Round 3
// baseline (450.876 us; speedup 1.0000x reference)
//
#include <hip/hip_runtime.h>
#include <math.h>

// Problem constants: B=4, S=128, D=512, H=8, DH=64, A=B*H=32
// ws layout (float offsets):
#define Pq     0
#define Pk1    262144
#define Pk2    524288
#define Pv1    786432
#define Pv2    1048576
#define Oqk1   1310720
#define Oqk2   1835008
#define Ok1k2  2359296
#define Oqq    2883584
#define Ok1k1  2887680
#define Ok2k2  2891776
#define OU     2895872      // 4096 x 4096 floats (64 MB)
#define OPart  19673088     // 4 x 262144 floats
// total ws need: 20721664 floats = ~79 MB

// ---------------------------------------------------------------- reductions
__device__ __forceinline__ float block_reduce_max(float v, float* s_red) {
    #pragma unroll
    for (int o = 32; o > 0; o >>= 1) v = fmaxf(v, __shfl_down(v, o, 64));
    int wid = threadIdx.x >> 6;
    if ((threadIdx.x & 63) == 0) s_red[wid] = v;
    __syncthreads();
    if (threadIdx.x == 0)
        s_red[4] = fmaxf(fmaxf(s_red[0], s_red[1]), fmaxf(s_red[2], s_red[3]));
    __syncthreads();
    return s_red[4];
}

__device__ __forceinline__ float block_reduce_sum(float v, float* s_red) {
    #pragma unroll
    for (int o = 32; o > 0; o >>= 1) v += __shfl_down(v, o, 64);
    int wid = threadIdx.x >> 6;
    if ((threadIdx.x & 63) == 0) s_red[wid] = v;
    __syncthreads();
    if (threadIdx.x == 0)
        s_red[4] = s_red[0] + s_red[1] + s_red[2] + s_red[3];
    __syncthreads();
    return s_red[4];
}

// ---------------------------------------------------------------- K1: projections
// 5 GEMMs: [512 rows, 512] @ [512, 512] + bias -> heads layout [32][128][64]
__global__ __launch_bounds__(256) void k_proj(
    const float* __restrict__ x, const float* __restrict__ y, const float* __restrict__ z,
    const float* __restrict__ Wq,  const float* __restrict__ bq,
    const float* __restrict__ Wk1, const float* __restrict__ bk1,
    const float* __restrict__ Wk2, const float* __restrict__ bk2,
    const float* __restrict__ Wv1, const float* __restrict__ bv1,
    const float* __restrict__ Wv2, const float* __restrict__ bv2,
    float* __restrict__ ws)
{
    int p = blockIdx.z;
    const float *src, *W, *bias; float* dst;
    switch (p) {
        case 0:  src = x; W = Wq;  bias = bq;  dst = ws + Pq;  break;
        case 1:  src = y; W = Wk1; bias = bk1; dst = ws + Pk1; break;
        case 2:  src = z; W = Wk2; bias = bk2; dst = ws + Pk2; break;
        case 3:  src = y; W = Wv1; bias = bv1; dst = ws + Pv1; break;
        default: src = z; W = Wv2; bias = bv2; dst = ws + Pv2; break;
    }
    int m0 = blockIdx.y * 64;
    int n0 = blockIdx.x * 64;
    __shared__ float As[64 * 36];
    __shared__ float Bs[32 * 68];
    int t  = threadIdx.x;
    int tx = t & 15, ty = t >> 4;
    float acc[4][4] = {};
    for (int kt = 0; kt < 512; kt += 32) {
        #pragma unroll
        for (int r = 0; r < 2; ++r) {
            int f = t + 256 * r;                 // 512 float4s for A (64x32)
            int row = f >> 3, c4 = (f & 7) * 4;
            *(float4*)&As[row * 36 + c4] = *(const float4*)&src[(m0 + row) * 512 + kt + c4];
        }
        #pragma unroll
        for (int r = 0; r < 2; ++r) {
            int f = t + 256 * r;                 // 512 float4s for B (32x64)
            int row = f >> 4, c4 = (f & 15) * 4;
            *(float4*)&Bs[row * 68 + c4] = *(const float4*)&W[(kt + row) * 512 + n0 + c4];
        }
        __syncthreads();
        #pragma unroll
        for (int kk = 0; kk < 32; ++kk) {
            float a0 = As[(ty * 4 + 0) * 36 + kk];
            float a1 = As[(ty * 4 + 1) * 36 + kk];
            float a2 = As[(ty * 4 + 2) * 36 + kk];
            float a3 = As[(ty * 4 + 3) * 36 + kk];
            float4 b = *(const float4*)&Bs[kk * 68 + tx * 4];
            acc[0][0] += a0 * b.x; acc[0][1] += a0 * b.y; acc[0][2] += a0 * b.z; acc[0][3] += a0 * b.w;
            acc[1][0] += a1 * b.x; acc[1][1] += a1 * b.y; acc[1][2] += a1 * b.z; acc[1][3] += a1 * b.w;
            acc[2][0] += a2 * b.x; acc[2][1] += a2 * b.y; acc[2][2] += a2 * b.z; acc[2][3] += a2 * b.w;
            acc[3][0] += a3 * b.x; acc[3][1] += a3 * b.y; acc[3][2] += a3 * b.z; acc[3][3] += a3 * b.w;
        }
        __syncthreads();
    }
    float4 b4 = *(const float4*)&bias[n0 + tx * 4];
    int h   = n0 >> 6;          // 64-col tiles align with heads
    int dh0 = tx * 4;
    #pragma unroll
    for (int mm = 0; mm < 4; ++mm) {
        int row = m0 + ty * 4 + mm;             // 0..511
        int b_ = row >> 7, s = row & 127;
        float4 o;
        o.x = acc[mm][0] + b4.x; o.y = acc[mm][1] + b4.y;
        o.z = acc[mm][2] + b4.z; o.w = acc[mm][3] + b4.w;
        *(float4*)&dst[((b_ * 8 + h) * 128 + s) * 64 + dh0] = o;
    }
}

// ---------------------------------------------------------------- K2: Gram matrices + norms
__global__ __launch_bounds__(256) void k_dots(float* ws)
{
    int a = blockIdx.x, mat = blockIdx.y;
    const float *lhs, *rhs; float* dst;
    if (mat == 0)      { lhs = ws + Pq  + a * 8192; rhs = ws + Pk1 + a * 8192; dst = ws + Oqk1  + a * 16384; }
    else if (mat == 1) { lhs = ws + Pq  + a * 8192; rhs = ws + Pk2 + a * 8192; dst = ws + Oqk2  + a * 16384; }
    else               { lhs = ws + Pk1 + a * 8192; rhs = ws + Pk2 + a * 8192; dst = ws + Ok1k2 + a * 16384; }
    __shared__ float Ls[128 * 65];
    __shared__ float Rs[128 * 65];
    int t = threadIdx.x;
    for (int r = 0; r < 8; ++r) {
        int f = t + 256 * r;                     // 2048 float4s
        int row = f >> 4, c4 = (f & 15) * 4;
        float4 v = *(const float4*)&lhs[row * 64 + c4];
        Ls[row * 65 + c4 + 0] = v.x; Ls[row * 65 + c4 + 1] = v.y;
        Ls[row * 65 + c4 + 2] = v.z; Ls[row * 65 + c4 + 3] = v.w;
        v = *(const float4*)&rhs[row * 64 + c4];
        Rs[row * 65 + c4 + 0] = v.x; Rs[row * 65 + c4 + 1] = v.y;
        Rs[row * 65 + c4 + 2] = v.z; Rs[row * 65 + c4 + 3] = v.w;
    }
    __syncthreads();
    int tx = t & 15, ty = t >> 4;                // 8x8 tile per thread
    float acc[8][8] = {};
    for (int dh = 0; dh < 64; ++dh) {
        float lv[8], rv[8];
        #pragma unroll
        for (int jj = 0; jj < 8; ++jj) lv[jj] = Ls[(ty * 8 + jj) * 65 + dh];
        #pragma unroll
        for (int kk = 0; kk < 8; ++kk) rv[kk] = Rs[(tx * 8 + kk) * 65 + dh];
        #pragma unroll
        for (int jj = 0; jj < 8; ++jj)
            #pragma unroll
            for (int kk = 0; kk < 8; ++kk)
                acc[jj][kk] += lv[jj] * rv[kk];
    }
    #pragma unroll
    for (int jj = 0; jj < 8; ++jj) {
        #pragma unroll
        for (int k4 = 0; k4 < 2; ++k4) {
            float4 o;
            o.x = acc[jj][k4 * 4 + 0]; o.y = acc[jj][k4 * 4 + 1];
            o.z = acc[jj][k4 * 4 + 2]; o.w = acc[jj][k4 * 4 + 3];
            *(float4*)&dst[(ty * 8 + jj) * 128 + tx * 8 + k4 * 4] = o;
        }
    }
    // norms: mat0 -> qq (lhs=q), k1k1 (rhs=k1); mat1 -> k2k2 (rhs=k2)
    if (mat == 0) {
        if (t < 128) {
            float s = 0;
            for (int dh = 0; dh < 64; ++dh) { float v = Ls[t * 65 + dh]; s += v * v; }
            ws[Oqq + a * 128 + t] = s;
        } else {
            int row = t - 128; float s = 0;
            for (int dh = 0; dh < 64; ++dh) { float v = Rs[row * 65 + dh]; s += v * v; }
            ws[Ok1k1 + a * 128 + row] = s;
        }
    } else if (mat == 1 && t >= 128) {
        int row = t - 128; float s = 0;
        for (int dh = 0; dh < 64; ++dh) { float v = Rs[row * 65 + dh]; s += v * v; }
        ws[Ok2k2 + a * 128 + row] = s;
    }
}

// ---------------------------------------------------------------- K3: per-(a,i) fused softmax + T + U
// grid (128 i, 32 a), 256 threads
__global__ __launch_bounds__(256) void k_main(float* ws)
{
    int i = blockIdx.x, a = blockIdx.y;
    const float* gv2   = ws + Pv2   + a * 8192;
    const float* gv1   = ws + Pv1   + a * 8192;
    const float* gk1k2 = ws + Ok1k2 + a * 16384;
    __shared__ float s_v[128 * 64];              // v2, later v1
    __shared__ float s_T[128 * 68];              // e-tiles (pad 33) early, T (pad 68) late
    __shared__ float s_qk1[128], s_qk2[128], s_k1k1[128], s_k2k2[128];
    __shared__ float s_red[8];
    int t = threadIdx.x;
    if (t < 128) {
        s_qk1[t]  = ws[Oqk1 + a * 16384 + i * 128 + t];
        s_qk2[t]  = ws[Oqk2 + a * 16384 + i * 128 + t];
        s_k1k1[t] = ws[Ok1k1 + a * 128 + t];
        s_k2k2[t] = ws[Ok2k2 + a * 128 + t];
    }
    float qq = ws[Oqq + a * 128 + i];
    for (int r = 0; r < 8; ++r) {
        int f = t + 256 * r;
        *(float4*)&s_v[f * 4] = *(const float4*)&gv2[f * 4];
    }
    __syncthreads();

    int jp = t >> 2, sq = t & 3;
    int j0 = jp * 2, sb = sq * 16;
    float Tacc[32];
    #pragma unroll
    for (int u = 0; u < 32; ++u) Tacc[u] = 0.f;
    float mrun = -INFINITY, Zp = 0.f;

    #pragma unroll 1
    for (int kt = 0; kt < 4; ++kt) {
        int k0 = kt * 32;
        float tmax = -INFINITY;
        #pragma unroll
        for (int r = 0; r < 16; ++r) {
            int idx = t + 256 * r;               // 4096 = 128j x 32kk
            int j = idx >> 5, kk = idx & 31;
            int k = k0 + kk;
            float c1 = s_qk1[j], c2 = s_qk2[k], c12 = gk1k2[j * 128 + k];
            float pre = c1 * c1 * s_k2k2[k] + c12 * c12 * qq + c2 * c2 * s_k1k1[j]
                      - 2.f * c1 * c2 * c12;
            if (isinf(pre)) pre = 55500.f;
            float lg = sqrtf(fmaxf(pre, 0.f));
            s_T[j * 33 + kk] = lg;
            tmax = fmaxf(tmax, lg);
        }
        float tile_max = block_reduce_max(tmax, s_red);   // syncs inside
        float m_new = fmaxf(mrun, tile_max);
        float scale = __expf(mrun - m_new);               // -inf -> 0 on first tile
        Zp *= scale;
        #pragma unroll
        for (int u = 0; u < 32; ++u) Tacc[u] *= scale;
        #pragma unroll
        for (int r = 0; r < 16; ++r) {
            int idx = t + 256 * r;
            int j = idx >> 5, kk = idx & 31;
            float e = __expf(s_T[j * 33 + kk] - m_new);
            s_T[j * 33 + kk] = e;
            Zp += e;
        }
        mrun = m_new;
        __syncthreads();
        // rank-32 update: T[j,s] += e[j,k] * v2[k,s]
        #pragma unroll
        for (int kk = 0; kk < 32; ++kk) {
            float e0 = s_T[j0 * 33 + kk];
            float e1 = s_T[j0 * 33 + 33 + kk];
            float4 v4[4];
            #pragma unroll
            for (int g = 0; g < 4; ++g)
                v4[g] = *(const float4*)&s_v[(k0 + kk) * 64 + sb + g * 4];
            const float* vv = (const float*)v4;
            #pragma unroll
            for (int ssi = 0; ssi < 16; ++ssi) {
                Tacc[ssi]      += e0 * vv[ssi];
                Tacc[16 + ssi] += e1 * vv[ssi];
            }
        }
        __syncthreads();
    }
    float Z = block_reduce_sum(Zp, s_red);

    // write T to LDS (pad 68), stage v1 over v2
    #pragma unroll
    for (int e_ = 0; e_ < 2; ++e_) {
        #pragma unroll
        for (int g = 0; g < 4; ++g) {
            float4 o;
            o.x = Tacc[e_ * 16 + g * 4 + 0]; o.y = Tacc[e_ * 16 + g * 4 + 1];
            o.z = Tacc[e_ * 16 + g * 4 + 2]; o.w = Tacc[e_ * 16 + g * 4 + 3];
            *(float4*)&s_T[(j0 + e_) * 68 + sb + g * 4] = o;
        }
    }
    for (int r = 0; r < 8; ++r) {
        int f = t + 256 * r;
        *(float4*)&s_v[f * 4] = *(const float4*)&gv1[f * 4];
    }
    __syncthreads();

    // U[r,s] = sum_j v1[j,r] * T[j,s],  scaled by 1/Z
    int st = t & 15, rt = t >> 4;
    int r0 = rt * 4, s0 = st * 4;
    float acc[4][4] = {};
    for (int j = 0; j < 128; ++j) {
        float4 va = *(const float4*)&s_v[j * 64 + r0];
        float4 vb = *(const float4*)&s_T[j * 68 + s0];
        const float* pa = (const float*)&va;
        const float* pb = (const float*)&vb;
        #pragma unroll
        for (int rr = 0; rr < 4; ++rr)
            #pragma unroll
            for (int ss = 0; ss < 4; ++ss)
                acc[rr][ss] += pa[rr] * pb[ss];
    }
    float invZ = 1.f / Z;
    float* gU = ws + OU + (a * 128 + i) * 4096;
    #pragma unroll
    for (int rr = 0; rr < 4; ++rr) {
        float4 o;
        o.x = acc[rr][0] * invZ; o.y = acc[rr][1] * invZ;
        o.z = acc[rr][2] * invZ; o.w = acc[rr][3] * invZ;
        *(float4*)&gU[(r0 + rr) * 64 + s0] = o;
    }
}

// ---------------------------------------------------------------- K4: out_partial = U @ B^T  (split-K)
// grid (64 m-tiles, 4 k-splits), 256 threads
__global__ __launch_bounds__(256) void k_bgemm(const float* __restrict__ Bw, float* ws)
{
    int m0 = blockIdx.x * 64;
    int ks = blockIdx.y * 1024;
    const float* gU = ws + OU;
    float* gP = ws + OPart + blockIdx.y * 262144;
    __shared__ float Us[64 * 36];
    __shared__ float Bs[64 * 36];
    int t = threadIdx.x;
    int qt = t & 15, mt = t >> 4;
    float acc[4][4] = {};
    for (int kt = ks; kt < ks + 1024; kt += 32) {
        #pragma unroll
        for (int r = 0; r < 2; ++r) {
            int f = t + 256 * r;                 // 512 float4s (64 rows x 8)
            int row = f >> 3, c4 = (f & 7) * 4;
            *(float4*)&Us[row * 36 + c4] = *(const float4*)&gU[(m0 + row) * 4096 + kt + c4];
            *(float4*)&Bs[row * 36 + c4] = *(const float4*)&Bw[row * 4096 + kt + c4];
        }
        __syncthreads();
        #pragma unroll
        for (int kk = 0; kk < 32; kk += 4) {
            float4 um[4], bq4[4];
            #pragma unroll
            for (int mm = 0; mm < 4; ++mm) um[mm] = *(const float4*)&Us[(mt * 4 + mm) * 36 + kk];
            #pragma unroll
            for (int qq = 0; qq < 4; ++qq) bq4[qq] = *(const float4*)&Bs[(qt * 4 + qq) * 36 + kk];
            #pragma unroll
            for (int mm = 0; mm < 4; ++mm)
                #pragma unroll
                for (int qq = 0; qq < 4; ++qq)
                    acc[mm][qq] += um[mm].x * bq4[qq].x + um[mm].y * bq4[qq].y
                                 + um[mm].z * bq4[qq].z + um[mm].w * bq4[qq].w;
        }
        __syncthreads();
    }
    #pragma unroll
    for (int mm = 0; mm < 4; ++mm) {
        float4 o;
        o.x = acc[mm][0]; o.y = acc[mm][1]; o.z = acc[mm][2]; o.w = acc[mm][3];
        *(float4*)&gP[(m0 + mt * 4 + mm) * 64 + qt * 4] = o;
    }
}

// ---------------------------------------------------------------- K5: reduce partials + scatter to [B,S,D]
__global__ __launch_bounds__(256) void k_reduce(const float* __restrict__ ws, float* __restrict__ out)
{
    int e0 = (blockIdx.x * 256 + threadIdx.x) * 4;      // 262144 total
    const float* gP = ws + OPart;
    float4 s = *(const float4*)&gP[e0];
    #pragma unroll
    for (int sp = 1; sp < 4; ++sp) {
        float4 v = *(const float4*)&gP[sp * 262144 + e0];
        s.x += v.x; s.y += v.y; s.z += v.z; s.w += v.w;
    }
    int m = e0 >> 6, q0 = e0 & 63;
    int a = m >> 7, i = m & 127;
    int b_ = a >> 3, h = a & 7;
    *(float4*)&out[b_ * 65536 + i * 512 + h * 64 + q0] = s;
}

// ---------------------------------------------------------------- launch
extern "C" void kernel_launch(void* const* d_in, const int* in_sizes, int n_in,
                              void* d_out, int out_size, void* d_ws, size_t ws_size,
                              hipStream_t stream)
{
    const float* x   = (const float*)d_in[0];
    const float* y   = (const float*)d_in[1];
    const float* z   = (const float*)d_in[2];
    const float* Bw  = (const float*)d_in[3];
    const float* Wq  = (const float*)d_in[4];
    const float* bq  = (const float*)d_in[5];
    const float* Wk1 = (const float*)d_in[6];
    const float* bk1 = (const float*)d_in[7];
    const float* Wk2 = (const float*)d_in[8];
    const float* bk2 = (const float*)d_in[9];
    const float* Wv1 = (const float*)d_in[10];
    const float* bv1 = (const float*)d_in[11];
    const float* Wv2 = (const float*)d_in[12];
    const float* bv2 = (const float*)d_in[13];
    float* ws = (float*)d_ws;
    float* out = (float*)d_out;

    k_proj<<<dim3(8, 8, 5), 256, 0, stream>>>(x, y, z, Wq, bq, Wk1, bk1, Wk2, bk2,
                                              Wv1, bv1, Wv2, bv2, ws);
    k_dots<<<dim3(32, 3), 256, 0, stream>>>(ws);
    k_main<<<dim3(128, 32), 256, 0, stream>>>(ws);
    k_bgemm<<<dim3(64, 4), 256, 0, stream>>>(Bw, ws);
    k_reduce<<<256, 256, 0, stream>>>(ws, out);
}

// Round 7
// 296.528 us; speedup vs baseline: 1.5205x; 1.5205x over previous
//
#include <hip/hip_runtime.h>
#include <math.h>

// Problem constants: B=4, S=128, D=512, H=8, DH=64, A=B*H=32
// ws layout (float offsets):
#define Pq     0
#define Pk1    262144
#define Pk2    524288
#define Pv1    786432       // fp16 v1^T, chunk-swizzled: [a][r=dh][j=seq], 16KB/head (bytes)
#define Pv2    1048576      // fp16 v2^T, chunk-swizzled: [a][dh][k=seq]
#define Oqk1   1310720
#define Oqk2   1835008
#define Ok1k2  2359296
#define Oqq    2883584
#define Ok1k1  2887680
#define Ok2k2  2891776
#define OU     2895872      // 4096 x 4096 floats (64 MB)
#define OPart  19673088     // 4 x 262144 floats

typedef _Float16 f16x8 __attribute__((ext_vector_type(8)));
typedef float    f32x4 __attribute__((ext_vector_type(4)));

// ---------------------------------------------------------------- reductions
__device__ __forceinline__ float block_reduce_max(float v, float* s_red) {
    #pragma unroll
    for (int o = 32; o > 0; o >>= 1) v = fmaxf(v, __shfl_down(v, o, 64));
    int wid = threadIdx.x >> 6;
    if ((threadIdx.x & 63) == 0) s_red[wid] = v;
    __syncthreads();
    if (threadIdx.x == 0)
        s_red[4] = fmaxf(fmaxf(s_red[0], s_red[1]), fmaxf(s_red[2], s_red[3]));
    __syncthreads();
    return s_red[4];
}

__device__ __forceinline__ float block_reduce_sum(float v, float* s_red) {
    #pragma unroll
    for (int o = 32; o > 0; o >>= 1) v += __shfl_down(v, o, 64);
    int wid = threadIdx.x >> 6;
    if ((threadIdx.x & 63) == 0) s_red[wid] = v;
    __syncthreads();
    if (threadIdx.x == 0)
        s_red[4] = s_red[0] + s_red[1] + s_red[2] + s_red[3];
    __syncthreads();
    return s_red[4];
}

// ---------------------------------------------------------------- K1: projections
// q/k1/k2 -> fp32 heads layout [32][128][64]; v1/v2 -> fp16 transposed swizzled
__global__ __launch_bounds__(256) void k_proj(
    const float* __restrict__ x, const float* __restrict__ y, const float* __restrict__ z,
    const float* __restrict__ Wq,  const float* __restrict__ bq,
    const float* __restrict__ Wk1, const float* __restrict__ bk1,
    const float* __restrict__ Wk2, const float* __restrict__ bk2,
    const float* __restrict__ Wv1, const float* __restrict__ bv1,
    const float* __restrict__ Wv2, const float* __restrict__ bv2,
    float* __restrict__ ws)
{
    int p = blockIdx.z;
    const float *src, *W, *bias; float* dst;
    switch (p) {
        case 0:  src = x; W = Wq;  bias = bq;  dst = ws + Pq;  break;
        case 1:  src = y; W = Wk1; bias = bk1; dst = ws + Pk1; break;
        case 2:  src = z; W = Wk2; bias = bk2; dst = ws + Pk2; break;
        case 3:  src = y; W = Wv1; bias = bv1; dst = ws + Pv1; break;
        default: src = z; W = Wv2; bias = bv2; dst = ws + Pv2; break;
    }
    int m0 = blockIdx.y * 64;
    int n0 = blockIdx.x * 64;
    __shared__ float As[64 * 36];
    __shared__ float Bs[32 * 68];
    int t  = threadIdx.x;
    int tx = t & 15, ty = t >> 4;
    float acc[4][4] = {};
    for (int kt = 0; kt < 512; kt += 32) {
        #pragma unroll
        for (int r = 0; r < 2; ++r) {
            int f = t + 256 * r;                 // 512 float4s for A (64x32)
            int row = f >> 3, c4 = (f & 7) * 4;
            *(float4*)&As[row * 36 + c4] = *(const float4*)&src[(m0 + row) * 512 + kt + c4];
        }
        #pragma unroll
        for (int r = 0; r < 2; ++r) {
            int f = t + 256 * r;                 // 512 float4s for B (32x64)
            int row = f >> 4, c4 = (f & 15) * 4;
            *(float4*)&Bs[row * 68 + c4] = *(const float4*)&W[(kt + row) * 512 + n0 + c4];
        }
        __syncthreads();
        #pragma unroll
        for (int kk = 0; kk < 32; ++kk) {
            float a0 = As[(ty * 4 + 0) * 36 + kk];
            float a1 = As[(ty * 4 + 1) * 36 + kk];
            float a2 = As[(ty * 4 + 2) * 36 + kk];
            float a3 = As[(ty * 4 + 3) * 36 + kk];
            float4 b = *(const float4*)&Bs[kk * 68 + tx * 4];
            acc[0][0] += a0 * b.x; acc[0][1] += a0 * b.y; acc[0][2] += a0 * b.z; acc[0][3] += a0 * b.w;
            acc[1][0] += a1 * b.x; acc[1][1] += a1 * b.y; acc[1][2] += a1 * b.z; acc[1][3] += a1 * b.w;
            acc[2][0] += a2 * b.x; acc[2][1] += a2 * b.y; acc[2][2] += a2 * b.z; acc[2][3] += a2 * b.w;
            acc[3][0] += a3 * b.x; acc[3][1] += a3 * b.y; acc[3][2] += a3 * b.z; acc[3][3] += a3 * b.w;
        }
        __syncthreads();
    }
    float4 b4 = *(const float4*)&bias[n0 + tx * 4];
    int hd  = n0 >> 6;           // 64-col tiles align with heads
    if (p >= 3) {
        // transposed fp16 [a][dh][seq], 16B-chunk XOR-swizzled by (dh&7)
        int b_ = m0 >> 7;        // 64-row tile lies within one b
        int aa = b_ * 8 + hd;
        int seq0 = (m0 & 127) + ty * 4;
        int cs = seq0 >> 3, os = seq0 & 7;       // chunk / offset (os in {0,4})
        char* dstb = (char*)dst + aa * 16384;
        const float bb[4] = { b4.x, b4.y, b4.z, b4.w };
        #pragma unroll
        for (int dd = 0; dd < 4; ++dd) {
            int dh = tx * 4 + dd;
            union { _Float16 f[4]; ushort4 u; } pk;
            pk.f[0] = (_Float16)(acc[0][dd] + bb[dd]);
            pk.f[1] = (_Float16)(acc[1][dd] + bb[dd]);
            pk.f[2] = (_Float16)(acc[2][dd] + bb[dd]);
            pk.f[3] = (_Float16)(acc[3][dd] + bb[dd]);
            *(ushort4*)(dstb + dh * 256 + ((cs ^ (dh & 7)) * 16) + os * 2) = pk.u;
        }
    } else {
        int dh0 = tx * 4;
        #pragma unroll
        for (int mm = 0; mm < 4; ++mm) {
            int row = m0 + ty * 4 + mm;             // 0..511
            int b_ = row >> 7, s = row & 127;
            float4 o;
            o.x = acc[mm][0] + b4.x; o.y = acc[mm][1] + b4.y;
            o.z = acc[mm][2] + b4.z; o.w = acc[mm][3] + b4.w;
            *(float4*)&dst[((b_ * 8 + hd) * 128 + s) * 64 + dh0] = o;
        }
    }
}

// ---------------------------------------------------------------- K2: Gram matrices + norms (unchanged)
__global__ __launch_bounds__(256) void k_dots(float* ws)
{
    int a = blockIdx.x, mat = blockIdx.y;
    const float *lhs, *rhs; float* dst;
    if (mat == 0)      { lhs = ws + Pq  + a * 8192; rhs = ws + Pk1 + a * 8192; dst = ws + Oqk1  + a * 16384; }
    else if (mat == 1) { lhs = ws + Pq  + a * 8192; rhs = ws + Pk2 + a * 8192; dst = ws + Oqk2  + a * 16384; }
    else               { lhs = ws + Pk1 + a * 8192; rhs = ws + Pk2 + a * 8192; dst = ws + Ok1k2 + a * 16384; }
    __shared__ float Ls[128 * 65];
    __shared__ float Rs[128 * 65];
    int t = threadIdx.x;
    for (int r = 0; r < 8; ++r) {
        int f = t + 256 * r;                     // 2048 float4s
        int row = f >> 4, c4 = (f & 15) * 4;
        float4 v = *(const float4*)&lhs[row * 64 + c4];
        Ls[row * 65 + c4 + 0] = v.x; Ls[row * 65 + c4 + 1] = v.y;
        Ls[row * 65 + c4 + 2] = v.z; Ls[row * 65 + c4 + 3] = v.w;
        v = *(const float4*)&rhs[row * 64 + c4];
        Rs[row * 65 + c4 + 0] = v.x; Rs[row * 65 + c4 + 1] = v.y;
        Rs[row * 65 + c4 + 2] = v.z; Rs[row * 65 + c4 + 3] = v.w;
    }
    __syncthreads();
    int tx = t & 15, ty = t >> 4;                // 8x8 tile per thread
    float acc[8][8] = {};
    for (int dh = 0; dh < 64; ++dh) {
        float lv[8], rv[8];
        #pragma unroll
        for (int jj = 0; jj < 8; ++jj) lv[jj] = Ls[(ty * 8 + jj) * 65 + dh];
        #pragma unroll
        for (int kk = 0; kk < 8; ++kk) rv[kk] = Rs[(tx * 8 + kk) * 65 + dh];
        #pragma unroll
        for (int jj = 0; jj < 8; ++jj)
            #pragma unroll
            for (int kk = 0; kk < 8; ++kk)
                acc[jj][kk] += lv[jj] * rv[kk];
    }
    #pragma unroll
    for (int jj = 0; jj < 8; ++jj) {
        #pragma unroll
        for (int k4 = 0; k4 < 2; ++k4) {
            float4 o;
            o.x = acc[jj][k4 * 4 + 0]; o.y = acc[jj][k4 * 4 + 1];
            o.z = acc[jj][k4 * 4 + 2]; o.w = acc[jj][k4 * 4 + 3];
            *(float4*)&dst[(ty * 8 + jj) * 128 + tx * 8 + k4 * 4] = o;
        }
    }
    if (mat == 0) {
        if (t < 128) {
            float s = 0;
            for (int dh = 0; dh < 64; ++dh) { float v = Ls[t * 65 + dh]; s += v * v; }
            ws[Oqq + a * 128 + t] = s;
        } else {
            int row = t - 128; float s = 0;
            for (int dh = 0; dh < 64; ++dh) { float v = Rs[row * 65 + dh]; s += v * v; }
            ws[Ok1k1 + a * 128 + row] = s;
        }
    } else if (mat == 1 && t >= 128) {
        int row = t - 128; float s = 0;
        for (int dh = 0; dh < 64; ++dh) { float v = Rs[row * 65 + dh]; s += v * v; }
        ws[Ok2k2 + a * 128 + row] = s;
    }
}

// ---------------------------------------------------------------- K3: per-(a,i) fused softmax + MFMA T + U
// grid (128 i, 32 a), 256 threads = 4 waves; wave w owns j-rows [w*32, w*32+32)
__global__ __launch_bounds__(256) void k_main(float* ws)
{
    int i = blockIdx.x, a = blockIdx.y;
    const float* gk1k2 = ws + Ok1k2 + a * 16384;
    __shared__ __align__(16) _Float16 s_v1t[8192];   // [64 r][128 j], chunk-swizzled
    __shared__ __align__(16) _Float16 s_v2t[8192];   // [64 dh][128 k], chunk-swizzled
    __shared__ __align__(16) _Float16 s_Tt[8192];    // [64 s][128 j], chunk-swizzled
    __shared__ __align__(16) float s_qk1[128];
    __shared__ __align__(16) float s_qk2[128];
    __shared__ __align__(16) float s_k1k1[128];
    __shared__ __align__(16) float s_k2k2[128];
    __shared__ float s_red[8];
    int t = threadIdx.x;
    int lane = t & 63, w = t >> 6;

    // async stage v1t/v2t (pre-swizzled fp16 written by k_proj); linear 16KB copies
    {
        const char* g1 = (const char*)(ws + Pv1) + a * 16384;
        const char* g2 = (const char*)(ws + Pv2) + a * 16384;
        #pragma unroll
        for (int c = 0; c < 4; ++c) {
            int ub = w * 4096 + c * 1024;            // wave-uniform LDS base
            int go = ub + lane * 16;                 // per-lane global offset
            __builtin_amdgcn_global_load_lds(
                (const __attribute__((address_space(1))) uint32_t*)(g1 + go),
                (__attribute__((address_space(3))) uint32_t*)((char*)s_v1t + ub), 16, 0, 0);
            __builtin_amdgcn_global_load_lds(
                (const __attribute__((address_space(1))) uint32_t*)(g2 + go),
                (__attribute__((address_space(3))) uint32_t*)((char*)s_v2t + ub), 16, 0, 0);
        }
    }
    if (t < 128) {
        s_qk1[t]  = ws[Oqk1 + a * 16384 + i * 128 + t];
        s_qk2[t]  = ws[Oqk2 + a * 16384 + i * 128 + t];
        s_k1k1[t] = ws[Ok1k1 + a * 128 + t];
        s_k2k2[t] = ws[Ok2k2 + a * 128 + t];
    }
    float qq = ws[Oqq + a * 128 + i];
    __syncthreads();    // drains global_load_lds, publishes qk rows

    int jb = w * 32;
    int lr = lane & 15;          // row/col within 16-tile
    int lg = lane >> 4;          // k-group (8 elems each)
    int j0 = jb + lr, j1 = jb + 16 + lr;
    float c1_0 = s_qk1[j0], c1_1 = s_qk1[j1];
    float n1_0 = s_k1k1[j0], n1_1 = s_k1k1[j1];

    f32x4 accT[2][4] = {};       // T fragments: rows jb+mt*16.., cols s=nt*16..
    float mrun = -INFINITY, Zp = 0.f;

    #pragma unroll 1
    for (int kt = 0; kt < 4; ++kt) {
        int k0 = kt * 32;
        int kb = k0 + lg * 8;
        float c2v[8], n2v[8], g0v[8], g1v[8];
        *(float4*)&c2v[0] = *(const float4*)&s_qk2[kb];
        *(float4*)&c2v[4] = *(const float4*)&s_qk2[kb + 4];
        *(float4*)&n2v[0] = *(const float4*)&s_k2k2[kb];
        *(float4*)&n2v[4] = *(const float4*)&s_k2k2[kb + 4];
        *(float4*)&g0v[0] = *(const float4*)&gk1k2[j0 * 128 + kb];
        *(float4*)&g0v[4] = *(const float4*)&gk1k2[j0 * 128 + kb + 4];
        *(float4*)&g1v[0] = *(const float4*)&gk1k2[j1 * 128 + kb];
        *(float4*)&g1v[4] = *(const float4*)&gk1k2[j1 * 128 + kb + 4];
        float lgt0[8], lgt1[8];
        float tmax = -INFINITY;
        #pragma unroll
        for (int u = 0; u < 8; ++u) {
            float c2 = c2v[u], n2 = n2v[u], c2sq = c2 * c2;
            float g = g0v[u];
            float pre = c1_0 * c1_0 * n2 + g * g * qq + c2sq * n1_0 - 2.f * c1_0 * c2 * g;
            if (isinf(pre)) pre = 55500.f;
            float l0 = sqrtf(fmaxf(pre, 0.f));
            g = g1v[u];
            pre = c1_1 * c1_1 * n2 + g * g * qq + c2sq * n1_1 - 2.f * c1_1 * c2 * g;
            if (isinf(pre)) pre = 55500.f;
            float l1 = sqrtf(fmaxf(pre, 0.f));
            lgt0[u] = l0; lgt1[u] = l1;
            tmax = fmaxf(tmax, fmaxf(l0, l1));
        }
        float tile_max = block_reduce_max(tmax, s_red);   // syncs inside
        float m_new = fmaxf(mrun, tile_max);
        float scale = __expf(mrun - m_new);               // first tile: exp(-inf)=0
        mrun = m_new;
        Zp *= scale;
        union { _Float16 f[8]; f16x8 v; } ea0, ea1;
        #pragma unroll
        for (int u = 0; u < 8; ++u) {
            float e0 = __expf(lgt0[u] - m_new);
            float e1 = __expf(lgt1[u] - m_new);
            Zp += e0 + e1;
            ea0.f[u] = (_Float16)e0;
            ea1.f[u] = (_Float16)e1;
        }
        #pragma unroll
        for (int mt = 0; mt < 2; ++mt)
            #pragma unroll
            for (int nt = 0; nt < 4; ++nt)
                accT[mt][nt] *= scale;
        int cb = (k0 >> 3) + lg;                          // logical 16B chunk in k
        #pragma unroll
        for (int nt = 0; nt < 4; ++nt) {
            int dh = nt * 16 + lr;
            f16x8 bV = *(const f16x8*)((const char*)s_v2t + dh * 256 + ((cb ^ (dh & 7)) * 16));
            accT[0][nt] = __builtin_amdgcn_mfma_f32_16x16x32_f16(ea0.v, bV, accT[0][nt], 0, 0, 0);
            accT[1][nt] = __builtin_amdgcn_mfma_f32_16x16x32_f16(ea1.v, bV, accT[1][nt], 0, 0, 0);
        }
    }
    float Z = block_reduce_sum(Zp, s_red);

    // write T^T to LDS fp16 [s][j] swizzled (D-frag: row j = base+(lg*4+reg), col s = nt*16+lr)
    #pragma unroll
    for (int mt = 0; mt < 2; ++mt) {
        int jw = jb + mt * 16 + lg * 4;          // 4 consecutive j
        int cj = jw >> 3, oj = jw & 7;           // oj in {0,4}
        #pragma unroll
        for (int nt = 0; nt < 4; ++nt) {
            int s = nt * 16 + lr;
            union { _Float16 f[4]; ushort4 u; } pk;
            f32x4 v = accT[mt][nt];
            pk.f[0] = (_Float16)v[0]; pk.f[1] = (_Float16)v[1];
            pk.f[2] = (_Float16)v[2]; pk.f[3] = (_Float16)v[3];
            *(ushort4*)((char*)s_Tt + s * 256 + ((cj ^ (s & 7)) * 16) + oj * 2) = pk.u;
        }
    }
    __syncthreads();

    // U = V1^T @ T : M=64 (r), N=64 (s), K=128 (j); wave w -> r rows [w*16, w*16+16)
    f32x4 accU[4] = {};
    int r = w * 16 + lr;
    #pragma unroll
    for (int ks = 0; ks < 4; ++ks) {
        int cj = ks * 4 + lg;
        f16x8 aV = *(const f16x8*)((const char*)s_v1t + r * 256 + ((cj ^ (r & 7)) * 16));
        #pragma unroll
        for (int nt = 0; nt < 4; ++nt) {
            int s = nt * 16 + lr;
            f16x8 bT = *(const f16x8*)((const char*)s_Tt + s * 256 + ((cj ^ (s & 7)) * 16));
            accU[nt] = __builtin_amdgcn_mfma_f32_16x16x32_f16(aV, bT, accU[nt], 0, 0, 0);
        }
    }
    float invZ = 1.f / Z;
    float* gU = ws + OU + (a * 128 + i) * 4096;
    #pragma unroll
    for (int nt = 0; nt < 4; ++nt) {
        int s = nt * 16 + lr;
        #pragma unroll
        for (int reg = 0; reg < 4; ++reg) {
            int rr = w * 16 + lg * 4 + reg;
            gU[rr * 64 + s] = accU[nt][reg] * invZ;
        }
    }
}

// ---------------------------------------------------------------- K4: out_partial = U @ B^T (split-K, unchanged)
__global__ __launch_bounds__(256) void k_bgemm(const float* __restrict__ Bw, float* ws)
{
    int m0 = blockIdx.x * 64;
    int ks = blockIdx.y * 1024;
    const float* gU = ws + OU;
    float* gP = ws + OPart + blockIdx.y * 262144;
    __shared__ float Us[64 * 36];
    __shared__ float Bs[64 * 36];
    int t = threadIdx.x;
    int qt = t & 15, mt = t >> 4;
    float acc[4][4] = {};
    for (int kt = ks; kt < ks + 1024; kt += 32) {
        #pragma unroll
        for (int r = 0; r < 2; ++r) {
            int f = t + 256 * r;                 // 512 float4s (64 rows x 8)
            int row = f >> 3, c4 = (f & 7) * 4;
            *(float4*)&Us[row * 36 + c4] = *(const float4*)&gU[(m0 + row) * 4096 + kt + c4];
            *(float4*)&Bs[row * 36 + c4] = *(const float4*)&Bw[row * 4096 + kt + c4];
        }
        __syncthreads();
        #pragma unroll
        for (int kk = 0; kk < 32; kk += 4) {
            float4 um[4], bq4[4];
            #pragma unroll
            for (int mm = 0; mm < 4; ++mm) um[mm] = *(const float4*)&Us[(mt * 4 + mm) * 36 + kk];
            #pragma unroll
            for (int qq = 0; qq < 4; ++qq) bq4[qq] = *(const float4*)&Bs[(qt * 4 + qq) * 36 + kk];
            #pragma unroll
            for (int mm = 0; mm < 4; ++mm)
                #pragma unroll
                for (int qq = 0; qq < 4; ++qq)
                    acc[mm][qq] += um[mm].x * bq4[qq].x + um[mm].y * bq4[qq].y
                                 + um[mm].z * bq4[qq].z + um[mm].w * bq4[qq].w;
        }
        __syncthreads();
    }
    #pragma unroll
    for (int mm = 0; mm < 4; ++mm) {
        float4 o;
        o.x = acc[mm][0]; o.y = acc[mm][1]; o.z = acc[mm][2]; o.w = acc[mm][3];
        *(float4*)&gP[(m0 + mt * 4 + mm) * 64 + qt * 4] = o;
    }
}

// ---------------------------------------------------------------- K5: reduce partials + scatter (unchanged)
__global__ __launch_bounds__(256) void k_reduce(const float* __restrict__ ws, float* __restrict__ out)
{
    int e0 = (blockIdx.x * 256 + threadIdx.x) * 4;      // 262144 total
    const float* gP = ws + OPart;
    float4 s = *(const float4*)&gP[e0];
    #pragma unroll
    for (int sp = 1; sp < 4; ++sp) {
        float4 v = *(const float4*)&gP[sp * 262144 + e0];
        s.x += v.x; s.y += v.y; s.z += v.z; s.w += v.w;
    }
    int m = e0 >> 6, q0 = e0 & 63;
    int a = m >> 7, i = m & 127;
    int b_ = a >> 3, h = a & 7;
    *(float4*)&out[b_ * 65536 + i * 512 + h * 64 + q0] = s;
}

// ---------------------------------------------------------------- launch
extern "C" void kernel_launch(void* const* d_in, const int* in_sizes, int n_in,
                              void* d_out, int out_size, void* d_ws, size_t ws_size,
                              hipStream_t stream)
{
    const float* x   = (const float*)d_in[0];
    const float* y   = (const float*)d_in[1];
    const float* z   = (const float*)d_in[2];
    const float* Bw  = (const float*)d_in[3];
    const float* Wq  = (const float*)d_in[4];
    const float* bq  = (const float*)d_in[5];
    const float* Wk1 = (const float*)d_in[6];
    const float* bk1 = (const float*)d_in[7];
    const float* Wk2 = (const float*)d_in[8];
    const float* bk2 = (const float*)d_in[9];
    const float* Wv1 = (const float*)d_in[10];
    const float* bv1 = (const float*)d_in[11];
    const float* Wv2 = (const float*)d_in[12];
    const float* bv2 = (const float*)d_in[13];
    float* ws = (float*)d_ws;
    float* out = (float*)d_out;

    k_proj<<<dim3(8, 8, 5), 256, 0, stream>>>(x, y, z, Wq, bq, Wk1, bk1, Wk2, bk2,
                                              Wv1, bv1, Wv2, bv2, ws);
    k_dots<<<dim3(32, 3), 256, 0, stream>>>(ws);
    k_main<<<dim3(128, 32), 256, 0, stream>>>(ws);
    k_bgemm<<<dim3(64, 4), 256, 0, stream>>>(Bw, ws);
    k_reduce<<<256, 256, 0, stream>>>(ws, out);
}

// Round 11
// 216.549 us; speedup vs baseline: 2.0821x; 1.3693x over previous
//
#include <hip/hip_runtime.h>
#include <math.h>

// Problem constants: B=4, S=128, D=512, H=8, DH=64, A=B*H=32
// ws layout (float offsets):
#define Pq     0
#define Pk1    262144
#define Pk2    524288
#define Pv1    786432       // fp16 v1^T, chunk-swizzled: [a][r=dh][j=seq], 16KB/head (bytes)
#define Pv2    1048576      // fp16 v2^T, chunk-swizzled: [a][dh][k=seq]
#define Oqk1   1310720      // qk1 * log2(e)
#define Oqk2   1835008      // qk2 * log2(e)
#define Ok1k2  2359296      // raw
#define Oqq    2883584      // qq * log2(e)^2
#define Ok1k1  2887680      // raw
#define Ok2k2  2891776      // raw
#define OU     2895872      // U as fp16 [4096 m][4096 k=r*64+s] (32 MB)
// split-K partials: 8 x 262144 floats at ws+0 (overwrites dead projection data)

#define LOG2E 1.44269504f

typedef _Float16 f16x8 __attribute__((ext_vector_type(8)));
typedef float    f32x4 __attribute__((ext_vector_type(4)));

// ---------------------------------------------------------------- reductions
__device__ __forceinline__ float block_reduce_max(float v, float* s_red) {
    #pragma unroll
    for (int o = 32; o > 0; o >>= 1) v = fmaxf(v, __shfl_down(v, o, 64));
    int wid = threadIdx.x >> 6;
    if ((threadIdx.x & 63) == 0) s_red[wid] = v;
    __syncthreads();
    if (threadIdx.x == 0)
        s_red[4] = fmaxf(fmaxf(s_red[0], s_red[1]), fmaxf(s_red[2], s_red[3]));
    __syncthreads();
    return s_red[4];
}

__device__ __forceinline__ float block_reduce_sum(float v, float* s_red) {
    #pragma unroll
    for (int o = 32; o > 0; o >>= 1) v += __shfl_down(v, o, 64);
    int wid = threadIdx.x >> 6;
    if ((threadIdx.x & 63) == 0) s_red[wid] = v;
    __syncthreads();
    if (threadIdx.x == 0)
        s_red[4] = s_red[0] + s_red[1] + s_red[2] + s_red[3];
    __syncthreads();
    return s_red[4];
}

// ---------------------------------------------------------------- K1: projections
// q/k1/k2 -> fp32 heads layout [32][128][64]; v1/v2 -> fp16 transposed swizzled
__global__ __launch_bounds__(256) void k_proj(
    const float* __restrict__ x, const float* __restrict__ y, const float* __restrict__ z,
    const float* __restrict__ Wq,  const float* __restrict__ bq,
    const float* __restrict__ Wk1, const float* __restrict__ bk1,
    const float* __restrict__ Wk2, const float* __restrict__ bk2,
    const float* __restrict__ Wv1, const float* __restrict__ bv1,
    const float* __restrict__ Wv2, const float* __restrict__ bv2,
    float* __restrict__ ws)
{
    int p = blockIdx.z;
    const float *src, *W, *bias; float* dst;
    switch (p) {
        case 0:  src = x; W = Wq;  bias = bq;  dst = ws + Pq;  break;
        case 1:  src = y; W = Wk1; bias = bk1; dst = ws + Pk1; break;
        case 2:  src = z; W = Wk2; bias = bk2; dst = ws + Pk2; break;
        case 3:  src = y; W = Wv1; bias = bv1; dst = ws + Pv1; break;
        default: src = z; W = Wv2; bias = bv2; dst = ws + Pv2; break;
    }
    int m0 = blockIdx.y * 64;
    int n0 = blockIdx.x * 64;
    __shared__ float As[64 * 36];
    __shared__ float Bs[32 * 68];
    int t  = threadIdx.x;
    int tx = t & 15, ty = t >> 4;
    float acc[4][4] = {};
    for (int kt = 0; kt < 512; kt += 32) {
        #pragma unroll
        for (int r = 0; r < 2; ++r) {
            int f = t + 256 * r;                 // 512 float4s for A (64x32)
            int row = f >> 3, c4 = (f & 7) * 4;
            *(float4*)&As[row * 36 + c4] = *(const float4*)&src[(m0 + row) * 512 + kt + c4];
        }
        #pragma unroll
        for (int r = 0; r < 2; ++r) {
            int f = t + 256 * r;                 // 512 float4s for B (32x64)
            int row = f >> 4, c4 = (f & 15) * 4;
            *(float4*)&Bs[row * 68 + c4] = *(const float4*)&W[(kt + row) * 512 + n0 + c4];
        }
        __syncthreads();
        #pragma unroll
        for (int kk = 0; kk < 32; ++kk) {
            float a0 = As[(ty * 4 + 0) * 36 + kk];
            float a1 = As[(ty * 4 + 1) * 36 + kk];
            float a2 = As[(ty * 4 + 2) * 36 + kk];
            float a3 = As[(ty * 4 + 3) * 36 + kk];
            float4 b = *(const float4*)&Bs[kk * 68 + tx * 4];
            acc[0][0] += a0 * b.x; acc[0][1] += a0 * b.y; acc[0][2] += a0 * b.z; acc[0][3] += a0 * b.w;
            acc[1][0] += a1 * b.x; acc[1][1] += a1 * b.y; acc[1][2] += a1 * b.z; acc[1][3] += a1 * b.w;
            acc[2][0] += a2 * b.x; acc[2][1] += a2 * b.y; acc[2][2] += a2 * b.z; acc[2][3] += a2 * b.w;
            acc[3][0] += a3 * b.x; acc[3][1] += a3 * b.y; acc[3][2] += a3 * b.z; acc[3][3] += a3 * b.w;
        }
        __syncthreads();
    }
    float4 b4 = *(const float4*)&bias[n0 + tx * 4];
    int hd  = n0 >> 6;           // 64-col tiles align with heads
    if (p >= 3) {
        // transposed fp16 [a][dh][seq], 16B-chunk XOR-swizzled by (dh&7)
        int b_ = m0 >> 7;        // 64-row tile lies within one b
        int aa = b_ * 8 + hd;
        int seq0 = (m0 & 127) + ty * 4;
        int cs = seq0 >> 3, os = seq0 & 7;       // chunk / offset (os in {0,4})
        char* dstb = (char*)dst + aa * 16384;
        const float bb[4] = { b4.x, b4.y, b4.z, b4.w };
        #pragma unroll
        for (int dd = 0; dd < 4; ++dd) {
            int dh = tx * 4 + dd;
            union { _Float16 f[4]; ushort4 u; } pk;
            pk.f[0] = (_Float16)(acc[0][dd] + bb[dd]);
            pk.f[1] = (_Float16)(acc[1][dd] + bb[dd]);
            pk.f[2] = (_Float16)(acc[2][dd] + bb[dd]);
            pk.f[3] = (_Float16)(acc[3][dd] + bb[dd]);
            *(ushort4*)(dstb + dh * 256 + ((cs ^ (dh & 7)) * 16) + os * 2) = pk.u;
        }
    } else {
        int dh0 = tx * 4;
        #pragma unroll
        for (int mm = 0; mm < 4; ++mm) {
            int row = m0 + ty * 4 + mm;             // 0..511
            int b_ = row >> 7, s = row & 127;
            float4 o;
            o.x = acc[mm][0] + b4.x; o.y = acc[mm][1] + b4.y;
            o.z = acc[mm][2] + b4.z; o.w = acc[mm][3] + b4.w;
            *(float4*)&dst[((b_ * 8 + hd) * 128 + s) * 64 + dh0] = o;
        }
    }
}

// ---------------------------------------------------------------- K2: Gram matrices + norms
// qk1/qk2 scaled by log2(e); qq scaled by log2(e)^2 (log2-domain logits downstream)
__global__ __launch_bounds__(256) void k_dots(float* ws)
{
    int a = blockIdx.x, mat = blockIdx.y;
    const float *lhs, *rhs; float* dst;
    if (mat == 0)      { lhs = ws + Pq  + a * 8192; rhs = ws + Pk1 + a * 8192; dst = ws + Oqk1  + a * 16384; }
    else if (mat == 1) { lhs = ws + Pq  + a * 8192; rhs = ws + Pk2 + a * 8192; dst = ws + Oqk2  + a * 16384; }
    else               { lhs = ws + Pk1 + a * 8192; rhs = ws + Pk2 + a * 8192; dst = ws + Ok1k2 + a * 16384; }
    float scl = (mat == 2) ? 1.f : LOG2E;
    __shared__ float Ls[128 * 65];
    __shared__ float Rs[128 * 65];
    int t = threadIdx.x;
    for (int r = 0; r < 8; ++r) {
        int f = t + 256 * r;                     // 2048 float4s
        int row = f >> 4, c4 = (f & 15) * 4;
        float4 v = *(const float4*)&lhs[row * 64 + c4];
        Ls[row * 65 + c4 + 0] = v.x; Ls[row * 65 + c4 + 1] = v.y;
        Ls[row * 65 + c4 + 2] = v.z; Ls[row * 65 + c4 + 3] = v.w;
        v = *(const float4*)&rhs[row * 64 + c4];
        Rs[row * 65 + c4 + 0] = v.x; Rs[row * 65 + c4 + 1] = v.y;
        Rs[row * 65 + c4 + 2] = v.z; Rs[row * 65 + c4 + 3] = v.w;
    }
    __syncthreads();
    int tx = t & 15, ty = t >> 4;                // 8x8 tile per thread
    float acc[8][8] = {};
    for (int dh = 0; dh < 64; ++dh) {
        float lv[8], rv[8];
        #pragma unroll
        for (int jj = 0; jj < 8; ++jj) lv[jj] = Ls[(ty * 8 + jj) * 65 + dh];
        #pragma unroll
        for (int kk = 0; kk < 8; ++kk) rv[kk] = Rs[(tx * 8 + kk) * 65 + dh];
        #pragma unroll
        for (int jj = 0; jj < 8; ++jj)
            #pragma unroll
            for (int kk = 0; kk < 8; ++kk)
                acc[jj][kk] += lv[jj] * rv[kk];
    }
    #pragma unroll
    for (int jj = 0; jj < 8; ++jj) {
        #pragma unroll
        for (int k4 = 0; k4 < 2; ++k4) {
            float4 o;
            o.x = acc[jj][k4 * 4 + 0] * scl; o.y = acc[jj][k4 * 4 + 1] * scl;
            o.z = acc[jj][k4 * 4 + 2] * scl; o.w = acc[jj][k4 * 4 + 3] * scl;
            *(float4*)&dst[(ty * 8 + jj) * 128 + tx * 8 + k4 * 4] = o;
        }
    }
    if (mat == 0) {
        if (t < 128) {
            float s = 0;
            for (int dh = 0; dh < 64; ++dh) { float v = Ls[t * 65 + dh]; s += v * v; }
            ws[Oqq + a * 128 + t] = s * (LOG2E * LOG2E);
        } else {
            int row = t - 128; float s = 0;
            for (int dh = 0; dh < 64; ++dh) { float v = Rs[row * 65 + dh]; s += v * v; }
            ws[Ok1k1 + a * 128 + row] = s;
        }
    } else if (mat == 1 && t >= 128) {
        int row = t - 128; float s = 0;
        for (int dh = 0; dh < 64; ++dh) { float v = Rs[row * 65 + dh]; s += v * v; }
        ws[Ok2k2 + a * 128 + row] = s;
    }
}

// ---------------------------------------------------------------- K3: per-(a,i) fused softmax + MFMA T + U
// grid (128 i, 32 a), 256 threads = 4 waves; wave w owns j-rows [w*32, w*32+32)
// Single-pass max: all 64 log2-domain logits held in registers; no online rescale.
__global__ __launch_bounds__(256) void k_main(float* ws)
{
    int i = blockIdx.x, a = blockIdx.y;
    const float* gk1k2 = ws + Ok1k2 + a * 16384;
    __shared__ __align__(16) _Float16 s_v1t[8192];   // [64 r][128 j], chunk-swizzled
    __shared__ __align__(16) _Float16 s_v2t[8192];   // [64 dh][128 k], chunk-swizzled
    __shared__ __align__(16) _Float16 s_Tt[8192];    // [64 s][128 j], chunk-swizzled
    __shared__ __align__(16) float s_qk1[128];
    __shared__ __align__(16) float s_qk2[128];
    __shared__ __align__(16) float s_k1k1[128];
    __shared__ __align__(16) float s_k2k2[128];
    __shared__ float s_red[8];
    int t = threadIdx.x;
    int lane = t & 63, w = t >> 6;

    // async stage v1t/v2t (pre-swizzled fp16 written by k_proj); linear 16KB copies
    {
        const char* g1 = (const char*)(ws + Pv1) + a * 16384;
        const char* g2 = (const char*)(ws + Pv2) + a * 16384;
        #pragma unroll
        for (int c = 0; c < 4; ++c) {
            int ub = w * 4096 + c * 1024;            // wave-uniform LDS base
            int go = ub + lane * 16;                 // per-lane global offset
            __builtin_amdgcn_global_load_lds(
                (const __attribute__((address_space(1))) uint32_t*)(g1 + go),
                (__attribute__((address_space(3))) uint32_t*)((char*)s_v1t + ub), 16, 0, 0);
            __builtin_amdgcn_global_load_lds(
                (const __attribute__((address_space(1))) uint32_t*)(g2 + go),
                (__attribute__((address_space(3))) uint32_t*)((char*)s_v2t + ub), 16, 0, 0);
        }
    }
    if (t < 128) {
        s_qk1[t]  = ws[Oqk1 + a * 16384 + i * 128 + t];
        s_qk2[t]  = ws[Oqk2 + a * 16384 + i * 128 + t];
        s_k1k1[t] = ws[Ok1k1 + a * 128 + t];
        s_k2k2[t] = ws[Ok2k2 + a * 128 + t];
    }
    float qq = ws[Oqq + a * 128 + i];                 // log2e^2-scaled
    __syncthreads();    // drains global_load_lds, publishes qk rows

    int jb = w * 32;
    int lr = lane & 15;          // row/col within 16-tile
    int lg = lane >> 4;          // k-group (8 elems each)
    int j0 = jb + lr, j1 = jb + 16 + lr;
    float c1_0 = s_qk1[j0], c1_1 = s_qk1[j1];        // log2e-scaled
    float n1_0 = s_k1k1[j0], n1_1 = s_k1k1[j1];

    // ---- Phase A: all logits (log2 domain) into registers
    float lgt[4][16];
    float tmax = -INFINITY;
    #pragma unroll
    for (int kt = 0; kt < 4; ++kt) {
        int kb = kt * 32 + lg * 8;
        float c2v[8], n2v[8], g0v[8], g1v[8];
        *(float4*)&c2v[0] = *(const float4*)&s_qk2[kb];
        *(float4*)&c2v[4] = *(const float4*)&s_qk2[kb + 4];
        *(float4*)&n2v[0] = *(const float4*)&s_k2k2[kb];
        *(float4*)&n2v[4] = *(const float4*)&s_k2k2[kb + 4];
        *(float4*)&g0v[0] = *(const float4*)&gk1k2[j0 * 128 + kb];
        *(float4*)&g0v[4] = *(const float4*)&gk1k2[j0 * 128 + kb + 4];
        *(float4*)&g1v[0] = *(const float4*)&gk1k2[j1 * 128 + kb];
        *(float4*)&g1v[4] = *(const float4*)&gk1k2[j1 * 128 + kb + 4];
        #pragma unroll
        for (int u = 0; u < 8; ++u) {
            float c2 = c2v[u], n2 = n2v[u], c2sq = c2 * c2;
            float g = g0v[u];
            float pre = c1_0 * c1_0 * n2 + g * g * qq + c2sq * n1_0 - 2.f * c1_0 * c2 * g;
            float l0 = sqrtf(fmaxf(pre, 0.f));
            g = g1v[u];
            pre = c1_1 * c1_1 * n2 + g * g * qq + c2sq * n1_1 - 2.f * c1_1 * c2 * g;
            float l1 = sqrtf(fmaxf(pre, 0.f));
            lgt[kt][u] = l0; lgt[kt][8 + u] = l1;
            tmax = fmaxf(tmax, fmaxf(l0, l1));
        }
    }
    float m2 = block_reduce_max(tmax, s_red);        // joint max (log2 domain)

    // ---- Phase C: exp2 + MFMA accumulate (no rescaling)
    f32x4 accT[2][4] = {};       // T fragments: rows jb+mt*16.., cols s=nt*16..
    float Zp = 0.f;
    #pragma unroll
    for (int kt = 0; kt < 4; ++kt) {
        union { _Float16 f[8]; f16x8 v; } ea0, ea1;
        #pragma unroll
        for (int u = 0; u < 8; ++u) {
            float e0 = exp2f(lgt[kt][u]     - m2);
            float e1 = exp2f(lgt[kt][8 + u] - m2);
            Zp += e0 + e1;
            ea0.f[u] = (_Float16)e0;
            ea1.f[u] = (_Float16)e1;
        }
        int cb = kt * 4 + lg;                         // logical 16B chunk in k
        #pragma unroll
        for (int nt = 0; nt < 4; ++nt) {
            int dh = nt * 16 + lr;
            f16x8 bV = *(const f16x8*)((const char*)s_v2t + dh * 256 + ((cb ^ (dh & 7)) * 16));
            accT[0][nt] = __builtin_amdgcn_mfma_f32_16x16x32_f16(ea0.v, bV, accT[0][nt], 0, 0, 0);
            accT[1][nt] = __builtin_amdgcn_mfma_f32_16x16x32_f16(ea1.v, bV, accT[1][nt], 0, 0, 0);
        }
    }

    // write T^T to LDS fp16 [s][j] swizzled (D-frag: row j = base+(lg*4+reg), col s = nt*16+lr)
    #pragma unroll
    for (int mt = 0; mt < 2; ++mt) {
        int jw = jb + mt * 16 + lg * 4;          // 4 consecutive j
        int cj = jw >> 3, oj = jw & 7;           // oj in {0,4}
        #pragma unroll
        for (int nt = 0; nt < 4; ++nt) {
            int s = nt * 16 + lr;
            union { _Float16 f[4]; ushort4 u; } pk;
            f32x4 v = accT[mt][nt];
            pk.f[0] = (_Float16)v[0]; pk.f[1] = (_Float16)v[1];
            pk.f[2] = (_Float16)v[2]; pk.f[3] = (_Float16)v[3];
            *(ushort4*)((char*)s_Tt + s * 256 + ((cj ^ (s & 7)) * 16) + oj * 2) = pk.u;
        }
    }
    // reduce_sum's internal barriers also order Tt writes before U reads
    float Z = block_reduce_sum(Zp, s_red);

    // U = V1^T @ T : M=64 (r), N=64 (s), K=128 (j); wave w -> r rows [w*16, w*16+16)
    f32x4 accU[4] = {};
    int r = w * 16 + lr;
    #pragma unroll
    for (int ks = 0; ks < 4; ++ks) {
        int cj = ks * 4 + lg;
        f16x8 aV = *(const f16x8*)((const char*)s_v1t + r * 256 + ((cj ^ (r & 7)) * 16));
        #pragma unroll
        for (int nt = 0; nt < 4; ++nt) {
            int s = nt * 16 + lr;
            f16x8 bT = *(const f16x8*)((const char*)s_Tt + s * 256 + ((cj ^ (s & 7)) * 16));
            accU[nt] = __builtin_amdgcn_mfma_f32_16x16x32_f16(aV, bT, accU[nt], 0, 0, 0);
        }
    }
    float invZ = 1.f / Z;
    ushort* gU = (ushort*)(ws + OU) + (size_t)(a * 128 + i) * 4096;
    #pragma unroll
    for (int nt = 0; nt < 4; ++nt) {
        int s = nt * 16 + lr;
        #pragma unroll
        for (int reg = 0; reg < 4; ++reg) {
            int rr = w * 16 + lg * 4 + reg;
            union { _Float16 h; ushort u; } cv;
            cv.h = (_Float16)(accU[nt][reg] * invZ);
            gU[rr * 64 + s] = cv.u;
        }
    }
}

// ---------------------------------------------------------------- K4: out_partial = U16 @ B^T (fp16 MFMA, split-K=8)
// grid (64 m-tiles, 8 k-splits), 256 threads = 4 waves; barrier-free K-loop
__global__ __launch_bounds__(256) void k_bgemm(const float* __restrict__ Bw, float* ws)
{
    int m0 = blockIdx.x * 64;
    int ks = blockIdx.y * 512;
    const ushort* U16 = (const ushort*)(ws + OU);
    float* gP = ws + blockIdx.y * 262144;            // partials over dead projection region
    __shared__ __align__(16) ushort sB[64 * 512];    // [64 q][512 k] fp16, XOR-swizzled, 64KB
    int t = threadIdx.x;
    int lane = t & 63, w = t >> 6;

    // stage B k-slice, fp32 -> fp16, swizzled: thread t -> row q=t>>2, k-range (t&3)*128
    {
        int q = t >> 2, kc = (t & 3) * 128;
        const float* src = Bw + q * 4096 + ks + kc;
        char* base = (char*)sB + q * 1024;
        #pragma unroll
        for (int g2 = 0; g2 < 16; ++g2) {            // one 16B chunk (8 fp16) per iter
            float4 a4 = *(const float4*)&src[g2 * 8];
            float4 b4 = *(const float4*)&src[g2 * 8 + 4];
            union { _Float16 f[8]; f16x8 v; } pk;
            pk.f[0] = (_Float16)a4.x; pk.f[1] = (_Float16)a4.y;
            pk.f[2] = (_Float16)a4.z; pk.f[3] = (_Float16)a4.w;
            pk.f[4] = (_Float16)b4.x; pk.f[5] = (_Float16)b4.y;
            pk.f[6] = (_Float16)b4.z; pk.f[7] = (_Float16)b4.w;
            int c = (kc >> 3) + g2;                  // chunk index 0..63
            *(f16x8*)(base + ((c ^ (q & 7)) * 16)) = pk.v;
        }
    }
    __syncthreads();

    int lr = lane & 15, lg = lane >> 4;
    int mrow = m0 + w * 16 + lr;
    const ushort* urow = U16 + (size_t)mrow * 4096 + ks + lg * 8;
    f32x4 acc[4] = {};
    #pragma unroll
    for (int kt = 0; kt < 16; ++kt) {
        f16x8 aU = *(const f16x8*)(urow + kt * 32);  // global direct (4 lanes = 64B line)
        int c = kt * 4 + lg;
        #pragma unroll
        for (int nt = 0; nt < 4; ++nt) {
            int q = nt * 16 + lr;
            f16x8 bB = *(const f16x8*)((const char*)sB + q * 1024 + ((c ^ (q & 7)) * 16));
            acc[nt] = __builtin_amdgcn_mfma_f32_16x16x32_f16(aU, bB, acc[nt], 0, 0, 0);
        }
    }
    // D: col=lane&15 -> q within tile, row=lg*4+reg -> m within 16
    #pragma unroll
    for (int nt = 0; nt < 4; ++nt) {
        #pragma unroll
        for (int reg = 0; reg < 4; ++reg) {
            int m = m0 + w * 16 + lg * 4 + reg;
            gP[m * 64 + nt * 16 + lr] = acc[nt][reg];
        }
    }
}

// ---------------------------------------------------------------- K5: reduce 8 partials + scatter to [B,S,D]
__global__ __launch_bounds__(256) void k_reduce(const float* __restrict__ ws, float* __restrict__ out)
{
    int e0 = (blockIdx.x * 256 + threadIdx.x) * 4;      // 262144 total
    float4 s = *(const float4*)&ws[e0];
    #pragma unroll
    for (int sp = 1; sp < 8; ++sp) {
        float4 v = *(const float4*)&ws[sp * 262144 + e0];
        s.x += v.x; s.y += v.y; s.z += v.z; s.w += v.w;
    }
    int m = e0 >> 6, q0 = e0 & 63;
    int a = m >> 7, i = m & 127;
    int b_ = a >> 3, h = a & 7;
    *(float4*)&out[b_ * 65536 + i * 512 + h * 64 + q0] = s;
}

// ---------------------------------------------------------------- launch
extern "C" void kernel_launch(void* const* d_in, const int* in_sizes, int n_in,
                              void* d_out, int out_size, void* d_ws, size_t ws_size,
                              hipStream_t stream)
{
    const float* x   = (const float*)d_in[0];
    const float* y   = (const float*)d_in[1];
    const float* z   = (const float*)d_in[2];
    const float* Bw  = (const float*)d_in[3];
    const float* Wq  = (const float*)d_in[4];
    const float* bq  = (const float*)d_in[5];
    const float* Wk1 = (const float*)d_in[6];
    const float* bk1 = (const float*)d_in[7];
    const float* Wk2 = (const float*)d_in[8];
    const float* bk2 = (const float*)d_in[9];
    const float* Wv1 = (const float*)d_in[10];
    const float* bv1 = (const float*)d_in[11];
    const float* Wv2 = (const float*)d_in[12];
    const float* bv2 = (const float*)d_in[13];
    float* ws = (float*)d_ws;
    float* out = (float*)d_out;

    k_proj<<<dim3(8, 8, 5), 256, 0, stream>>>(x, y, z, Wq, bq, Wk1, bk1, Wk2, bk2,
                                              Wv1, bv1, Wv2, bv2, ws);
    k_dots<<<dim3(32, 3), 256, 0, stream>>>(ws);
    k_main<<<dim3(128, 32), 256, 0, stream>>>(ws);
    k_bgemm<<<dim3(64, 8), 256, 0, stream>>>(Bw, ws);
    k_reduce<<<256, 256, 0, stream>>>(ws, out);
}

// Round 12
// 200.855 us; speedup vs baseline: 2.2448x; 1.0781x over previous
//
#include <hip/hip_runtime.h>
#include <math.h>

// Problem constants: B=4, S=128, D=512, H=8, DH=64, A=B*H=32
// ws layout (float offsets):
#define Pq     0
#define Pk1    262144
#define Pk2    524288
#define Pv1    786432       // fp16 v1^T, chunk-swizzled: [a][r=dh][j=seq], 16KB/head (bytes)
#define Pv2    1048576      // fp16 v2^T, chunk-swizzled: [a][dh][k=seq]
#define Oqk1   1310720      // qk1 * log2(e)
#define Oqk2   1835008      // qk2 * log2(e)
#define Ok1k2  2359296      // raw
#define Oqq    2883584      // qq * log2(e)^2
#define Ok1k1  2887680      // raw
#define Ok2k2  2891776      // raw
#define OU     2895872      // U as fp16 [4096 m][4096 k=r*64+s] (32 MB)
// split-K partials: 8 x 262144 floats at ws+0 (overwrites dead projection data)

#define LOG2E 1.44269504f

typedef _Float16 f16x8 __attribute__((ext_vector_type(8)));
typedef float    f32x4 __attribute__((ext_vector_type(4)));

// ---------------------------------------------------------------- reductions
__device__ __forceinline__ float block_reduce_max(float v, float* s_red) {
    #pragma unroll
    for (int o = 32; o > 0; o >>= 1) v = fmaxf(v, __shfl_down(v, o, 64));
    int wid = threadIdx.x >> 6;
    if ((threadIdx.x & 63) == 0) s_red[wid] = v;
    __syncthreads();
    if (threadIdx.x == 0)
        s_red[4] = fmaxf(fmaxf(s_red[0], s_red[1]), fmaxf(s_red[2], s_red[3]));
    __syncthreads();
    return s_red[4];
}

__device__ __forceinline__ float block_reduce_sum(float v, float* s_red) {
    #pragma unroll
    for (int o = 32; o > 0; o >>= 1) v += __shfl_down(v, o, 64);
    int wid = threadIdx.x >> 6;
    if ((threadIdx.x & 63) == 0) s_red[wid] = v;
    __syncthreads();
    if (threadIdx.x == 0)
        s_red[4] = s_red[0] + s_red[1] + s_red[2] + s_red[3];
    __syncthreads();
    return s_red[4];
}

// ---------------------------------------------------------------- K1: projections
// q/k1/k2 -> fp32 heads layout [32][128][64]; v1/v2 -> fp16 transposed swizzled
__global__ __launch_bounds__(256) void k_proj(
    const float* __restrict__ x, const float* __restrict__ y, const float* __restrict__ z,
    const float* __restrict__ Wq,  const float* __restrict__ bq,
    const float* __restrict__ Wk1, const float* __restrict__ bk1,
    const float* __restrict__ Wk2, const float* __restrict__ bk2,
    const float* __restrict__ Wv1, const float* __restrict__ bv1,
    const float* __restrict__ Wv2, const float* __restrict__ bv2,
    float* __restrict__ ws)
{
    int p = blockIdx.z;
    const float *src, *W, *bias; float* dst;
    switch (p) {
        case 0:  src = x; W = Wq;  bias = bq;  dst = ws + Pq;  break;
        case 1:  src = y; W = Wk1; bias = bk1; dst = ws + Pk1; break;
        case 2:  src = z; W = Wk2; bias = bk2; dst = ws + Pk2; break;
        case 3:  src = y; W = Wv1; bias = bv1; dst = ws + Pv1; break;
        default: src = z; W = Wv2; bias = bv2; dst = ws + Pv2; break;
    }
    int m0 = blockIdx.y * 64;
    int n0 = blockIdx.x * 64;
    __shared__ float As[64 * 36];
    __shared__ float Bs[32 * 68];
    int t  = threadIdx.x;
    int tx = t & 15, ty = t >> 4;
    float acc[4][4] = {};
    for (int kt = 0; kt < 512; kt += 32) {
        #pragma unroll
        for (int r = 0; r < 2; ++r) {
            int f = t + 256 * r;                 // 512 float4s for A (64x32)
            int row = f >> 3, c4 = (f & 7) * 4;
            *(float4*)&As[row * 36 + c4] = *(const float4*)&src[(m0 + row) * 512 + kt + c4];
        }
        #pragma unroll
        for (int r = 0; r < 2; ++r) {
            int f = t + 256 * r;                 // 512 float4s for B (32x64)
            int row = f >> 4, c4 = (f & 15) * 4;
            *(float4*)&Bs[row * 68 + c4] = *(const float4*)&W[(kt + row) * 512 + n0 + c4];
        }
        __syncthreads();
        #pragma unroll
        for (int kk = 0; kk < 32; ++kk) {
            float a0 = As[(ty * 4 + 0) * 36 + kk];
            float a1 = As[(ty * 4 + 1) * 36 + kk];
            float a2 = As[(ty * 4 + 2) * 36 + kk];
            float a3 = As[(ty * 4 + 3) * 36 + kk];
            float4 b = *(const float4*)&Bs[kk * 68 + tx * 4];
            acc[0][0] += a0 * b.x; acc[0][1] += a0 * b.y; acc[0][2] += a0 * b.z; acc[0][3] += a0 * b.w;
            acc[1][0] += a1 * b.x; acc[1][1] += a1 * b.y; acc[1][2] += a1 * b.z; acc[1][3] += a1 * b.w;
            acc[2][0] += a2 * b.x; acc[2][1] += a2 * b.y; acc[2][2] += a2 * b.z; acc[2][3] += a2 * b.w;
            acc[3][0] += a3 * b.x; acc[3][1] += a3 * b.y; acc[3][2] += a3 * b.z; acc[3][3] += a3 * b.w;
        }
        __syncthreads();
    }
    float4 b4 = *(const float4*)&bias[n0 + tx * 4];
    int hd  = n0 >> 6;           // 64-col tiles align with heads
    if (p >= 3) {
        // transposed fp16 [a][dh][seq], 16B-chunk XOR-swizzled by (dh&7)
        int b_ = m0 >> 7;        // 64-row tile lies within one b
        int aa = b_ * 8 + hd;
        int seq0 = (m0 & 127) + ty * 4;
        int cs = seq0 >> 3, os = seq0 & 7;       // chunk / offset (os in {0,4})
        char* dstb = (char*)dst + aa * 16384;
        const float bb[4] = { b4.x, b4.y, b4.z, b4.w };
        #pragma unroll
        for (int dd = 0; dd < 4; ++dd) {
            int dh = tx * 4 + dd;
            union { _Float16 f[4]; ushort4 u; } pk;
            pk.f[0] = (_Float16)(acc[0][dd] + bb[dd]);
            pk.f[1] = (_Float16)(acc[1][dd] + bb[dd]);
            pk.f[2] = (_Float16)(acc[2][dd] + bb[dd]);
            pk.f[3] = (_Float16)(acc[3][dd] + bb[dd]);
            *(ushort4*)(dstb + dh * 256 + ((cs ^ (dh & 7)) * 16) + os * 2) = pk.u;
        }
    } else {
        int dh0 = tx * 4;
        #pragma unroll
        for (int mm = 0; mm < 4; ++mm) {
            int row = m0 + ty * 4 + mm;             // 0..511
            int b_ = row >> 7, s = row & 127;
            float4 o;
            o.x = acc[mm][0] + b4.x; o.y = acc[mm][1] + b4.y;
            o.z = acc[mm][2] + b4.z; o.w = acc[mm][3] + b4.w;
            *(float4*)&dst[((b_ * 8 + hd) * 128 + s) * 64 + dh0] = o;
        }
    }
}

// ---------------------------------------------------------------- K2: Gram matrices + norms
// qk1/qk2 scaled by log2(e); qq scaled by log2(e)^2 (log2-domain logits downstream)
__global__ __launch_bounds__(256) void k_dots(float* ws)
{
    int a = blockIdx.x, mat = blockIdx.y;
    const float *lhs, *rhs; float* dst;
    if (mat == 0)      { lhs = ws + Pq  + a * 8192; rhs = ws + Pk1 + a * 8192; dst = ws + Oqk1  + a * 16384; }
    else if (mat == 1) { lhs = ws + Pq  + a * 8192; rhs = ws + Pk2 + a * 8192; dst = ws + Oqk2  + a * 16384; }
    else               { lhs = ws + Pk1 + a * 8192; rhs = ws + Pk2 + a * 8192; dst = ws + Ok1k2 + a * 16384; }
    float scl = (mat == 2) ? 1.f : LOG2E;
    __shared__ float Ls[128 * 65];
    __shared__ float Rs[128 * 65];
    int t = threadIdx.x;
    for (int r = 0; r < 8; ++r) {
        int f = t + 256 * r;                     // 2048 float4s
        int row = f >> 4, c4 = (f & 15) * 4;
        float4 v = *(const float4*)&lhs[row * 64 + c4];
        Ls[row * 65 + c4 + 0] = v.x; Ls[row * 65 + c4 + 1] = v.y;
        Ls[row * 65 + c4 + 2] = v.z; Ls[row * 65 + c4 + 3] = v.w;
        v = *(const float4*)&rhs[row * 64 + c4];
        Rs[row * 65 + c4 + 0] = v.x; Rs[row * 65 + c4 + 1] = v.y;
        Rs[row * 65 + c4 + 2] = v.z; Rs[row * 65 + c4 + 3] = v.w;
    }
    __syncthreads();
    int tx = t & 15, ty = t >> 4;                // 8x8 tile per thread
    float acc[8][8] = {};
    for (int dh = 0; dh < 64; ++dh) {
        float lv[8], rv[8];
        #pragma unroll
        for (int jj = 0; jj < 8; ++jj) lv[jj] = Ls[(ty * 8 + jj) * 65 + dh];
        #pragma unroll
        for (int kk = 0; kk < 8; ++kk) rv[kk] = Rs[(tx * 8 + kk) * 65 + dh];
        #pragma unroll
        for (int jj = 0; jj < 8; ++jj)
            #pragma unroll
            for (int kk = 0; kk < 8; ++kk)
                acc[jj][kk] += lv[jj] * rv[kk];
    }
    #pragma unroll
    for (int jj = 0; jj < 8; ++jj) {
        #pragma unroll
        for (int k4 = 0; k4 < 2; ++k4) {
            float4 o;
            o.x = acc[jj][k4 * 4 + 0] * scl; o.y = acc[jj][k4 * 4 + 1] * scl;
            o.z = acc[jj][k4 * 4 + 2] * scl; o.w = acc[jj][k4 * 4 + 3] * scl;
            *(float4*)&dst[(ty * 8 + jj) * 128 + tx * 8 + k4 * 4] = o;
        }
    }
    if (mat == 0) {
        if (t < 128) {
            float s = 0;
            for (int dh = 0; dh < 64; ++dh) { float v = Ls[t * 65 + dh]; s += v * v; }
            ws[Oqq + a * 128 + t] = s * (LOG2E * LOG2E);
        } else {
            int row = t - 128; float s = 0;
            for (int dh = 0; dh < 64; ++dh) { float v = Rs[row * 65 + dh]; s += v * v; }
            ws[Ok1k1 + a * 128 + row] = s;
        }
    } else if (mat == 1 && t >= 128) {
        int row = t - 128; float s = 0;
        for (int dh = 0; dh < 64; ++dh) { float v = Rs[row * 65 + dh]; s += v * v; }
        ws[Ok2k2 + a * 128 + row] = s;
    }
}

// ---------------------------------------------------------------- K3: per-(a,i) fused softmax + MFMA T + U
// grid (128 i, 32 a), 256 threads = 4 waves; wave w owns j-rows [w*32, w*32+32)
// Raw v_sqrt/v_exp/cvt_pkrtz via inline asm; factored logit polynomial:
//   pre = c1^2*n2 + beta*c2^2 + qq*(g - alpha*c2)^2,  alpha=c1/qq, beta=n1-c1^2/qq (>=0 by C-S)
// LDS: T^T overlays the v2 buffer after all v2 reads complete (reduce_sum barrier).
__global__ __launch_bounds__(256) void k_main(float* ws)
{
    int i = blockIdx.x, a = blockIdx.y;
    const float* gk1k2 = ws + Ok1k2 + a * 16384;
    __shared__ __align__(16) _Float16 s_v1t[8192];   // [64 r][128 j], chunk-swizzled
    __shared__ __align__(16) _Float16 s_kv[8192];    // v2^T early, T^T late (overlay)
    __shared__ __align__(16) float s_qk1[128];
    __shared__ __align__(16) float s_qk2[128];
    __shared__ __align__(16) float s_k1k1[128];
    __shared__ __align__(16) float s_k2k2[128];
    __shared__ float s_red[8];
    int t = threadIdx.x;
    int lane = t & 63, w = t >> 6;

    // async stage v1t -> s_v1t, v2t -> s_kv (pre-swizzled fp16 from k_proj)
    {
        const char* g1 = (const char*)(ws + Pv1) + a * 16384;
        const char* g2 = (const char*)(ws + Pv2) + a * 16384;
        #pragma unroll
        for (int c = 0; c < 4; ++c) {
            int ub = w * 4096 + c * 1024;            // wave-uniform LDS base
            int go = ub + lane * 16;                 // per-lane global offset
            __builtin_amdgcn_global_load_lds(
                (const __attribute__((address_space(1))) uint32_t*)(g1 + go),
                (__attribute__((address_space(3))) uint32_t*)((char*)s_v1t + ub), 16, 0, 0);
            __builtin_amdgcn_global_load_lds(
                (const __attribute__((address_space(1))) uint32_t*)(g2 + go),
                (__attribute__((address_space(3))) uint32_t*)((char*)s_kv + ub), 16, 0, 0);
        }
    }
    if (t < 128) {
        s_qk1[t]  = ws[Oqk1 + a * 16384 + i * 128 + t];
        s_qk2[t]  = ws[Oqk2 + a * 16384 + i * 128 + t];
        s_k1k1[t] = ws[Ok1k1 + a * 128 + t];
        s_k2k2[t] = ws[Ok2k2 + a * 128 + t];
    }
    float qq = ws[Oqq + a * 128 + i];                 // log2e^2-scaled
    __syncthreads();    // drains global_load_lds, publishes qk rows

    int jb = w * 32;
    int lr = lane & 15;          // row/col within 16-tile
    int lg = lane >> 4;          // k-group (8 elems each)
    int j0 = jb + lr, j1 = jb + 16 + lr;
    float c1_0 = s_qk1[j0], c1_1 = s_qk1[j1];        // log2e-scaled
    float n1_0 = s_k1k1[j0], n1_1 = s_k1k1[j1];
    float rq  = 1.0f / qq;
    float na0 = -(c1_0 * rq), na1 = -(c1_1 * rq);    // -alpha
    float be0 = fmaf(c1_0, na0, n1_0);               // beta >= 0 (Cauchy-Schwarz)
    float be1 = fmaf(c1_1, na1, n1_1);
    float sq0 = c1_0 * c1_0, sq1 = c1_1 * c1_1;

    // ---- Phase A: all logits (log2 domain) into registers
    float lgt[4][16];
    float tmax = 0.f;            // logits >= 0
    #pragma unroll
    for (int kt = 0; kt < 4; ++kt) {
        int kb = kt * 32 + lg * 8;
        float c2v[8], n2v[8], g0v[8], g1v[8];
        *(float4*)&c2v[0] = *(const float4*)&s_qk2[kb];
        *(float4*)&c2v[4] = *(const float4*)&s_qk2[kb + 4];
        *(float4*)&n2v[0] = *(const float4*)&s_k2k2[kb];
        *(float4*)&n2v[4] = *(const float4*)&s_k2k2[kb + 4];
        *(float4*)&g0v[0] = *(const float4*)&gk1k2[j0 * 128 + kb];
        *(float4*)&g0v[4] = *(const float4*)&gk1k2[j0 * 128 + kb + 4];
        *(float4*)&g1v[0] = *(const float4*)&gk1k2[j1 * 128 + kb];
        *(float4*)&g1v[4] = *(const float4*)&gk1k2[j1 * 128 + kb + 4];
        #pragma unroll
        for (int u = 0; u < 8; ++u) {
            float c2 = c2v[u], n2 = n2v[u];
            float c2sq = c2 * c2;
            float h0 = fmaf(be0, c2sq, sq0 * n2);
            float h1 = fmaf(be1, c2sq, sq1 * n2);
            float t0 = fmaf(na0, c2, g0v[u]);
            float t1 = fmaf(na1, c2, g1v[u]);
            float p0 = fmaxf(fmaf(qq * t0, t0, h0), 0.f);
            float p1 = fmaxf(fmaf(qq * t1, t1, h1), 0.f);
            float l0, l1;
            asm("v_sqrt_f32 %0, %1" : "=v"(l0) : "v"(p0));
            asm("v_sqrt_f32 %0, %1" : "=v"(l1) : "v"(p1));
            lgt[kt][u] = l0; lgt[kt][8 + u] = l1;
            tmax = fmaxf(tmax, fmaxf(l0, l1));
        }
    }
    float m2 = block_reduce_max(tmax, s_red);        // joint max (log2 domain)

    // ---- Phase C: raw exp2 + pack-convert + MFMA accumulate (no rescaling)
    f32x4 accT[2][4] = {};       // T fragments: rows jb+mt*16.., cols s=nt*16..
    float Zp = 0.f;
    #pragma unroll
    for (int kt = 0; kt < 4; ++kt) {
        union { f16x8 v; unsigned int u32[4]; } ea0, ea1;
        #pragma unroll
        for (int u = 0; u < 8; u += 2) {
            float x0 = lgt[kt][u]     - m2, x1 = lgt[kt][u + 1]     - m2;
            float x2 = lgt[kt][8 + u] - m2, x3 = lgt[kt][8 + u + 1] - m2;
            float e0, e1, e2, e3;
            asm("v_exp_f32 %0, %1" : "=v"(e0) : "v"(x0));
            asm("v_exp_f32 %0, %1" : "=v"(e1) : "v"(x1));
            asm("v_exp_f32 %0, %1" : "=v"(e2) : "v"(x2));
            asm("v_exp_f32 %0, %1" : "=v"(e3) : "v"(x3));
            Zp += (e0 + e1) + (e2 + e3);
            unsigned int r01, r23;
            asm("v_cvt_pkrtz_f16_f32 %0, %1, %2" : "=v"(r01) : "v"(e0), "v"(e1));
            asm("v_cvt_pkrtz_f16_f32 %0, %1, %2" : "=v"(r23) : "v"(e2), "v"(e3));
            ea0.u32[u >> 1] = r01;
            ea1.u32[u >> 1] = r23;
        }
        int cb = kt * 4 + lg;                         // logical 16B chunk in k
        #pragma unroll
        for (int nt = 0; nt < 4; ++nt) {
            int dh = nt * 16 + lr;
            f16x8 bV = *(const f16x8*)((const char*)s_kv + dh * 256 + ((cb ^ (dh & 7)) * 16));
            accT[0][nt] = __builtin_amdgcn_mfma_f32_16x16x32_f16(ea0.v, bV, accT[0][nt], 0, 0, 0);
            accT[1][nt] = __builtin_amdgcn_mfma_f32_16x16x32_f16(ea1.v, bV, accT[1][nt], 0, 0, 0);
        }
    }

    // reduce_sum's first barrier guarantees ALL waves' v2 (s_kv) reads are done
    float Z = block_reduce_sum(Zp, s_red);

    // write T^T overlaying s_kv: fp16 [s][j] swizzled (D-frag: row j=base+lg*4+reg, col s=nt*16+lr)
    #pragma unroll
    for (int mt = 0; mt < 2; ++mt) {
        int jw = jb + mt * 16 + lg * 4;          // 4 consecutive j
        int cj = jw >> 3, oj = jw & 7;           // oj in {0,4}
        #pragma unroll
        for (int nt = 0; nt < 4; ++nt) {
            int s = nt * 16 + lr;
            union { _Float16 f[4]; ushort4 u; } pk;
            f32x4 v = accT[mt][nt];
            pk.f[0] = (_Float16)v[0]; pk.f[1] = (_Float16)v[1];
            pk.f[2] = (_Float16)v[2]; pk.f[3] = (_Float16)v[3];
            *(ushort4*)((char*)s_kv + s * 256 + ((cj ^ (s & 7)) * 16) + oj * 2) = pk.u;
        }
    }
    __syncthreads();                             // T^T visible to all waves

    // U = V1^T @ T : M=64 (r), N=64 (s), K=128 (j); wave w -> r rows [w*16, w*16+16)
    f32x4 accU[4] = {};
    int r = w * 16 + lr;
    #pragma unroll
    for (int ks = 0; ks < 4; ++ks) {
        int cj = ks * 4 + lg;
        f16x8 aV = *(const f16x8*)((const char*)s_v1t + r * 256 + ((cj ^ (r & 7)) * 16));
        #pragma unroll
        for (int nt = 0; nt < 4; ++nt) {
            int s = nt * 16 + lr;
            f16x8 bT = *(const f16x8*)((const char*)s_kv + s * 256 + ((cj ^ (s & 7)) * 16));
            accU[nt] = __builtin_amdgcn_mfma_f32_16x16x32_f16(aV, bT, accU[nt], 0, 0, 0);
        }
    }
    float invZ = 1.f / Z;
    ushort* gU = (ushort*)(ws + OU) + (size_t)(a * 128 + i) * 4096;
    #pragma unroll
    for (int nt = 0; nt < 4; ++nt) {
        int s = nt * 16 + lr;
        #pragma unroll
        for (int reg = 0; reg < 4; ++reg) {
            int rr = w * 16 + lg * 4 + reg;
            union { _Float16 h; ushort u; } cv;
            cv.h = (_Float16)(accU[nt][reg] * invZ);
            gU[rr * 64 + s] = cv.u;
        }
    }
}

// ---------------------------------------------------------------- K4: out_partial = U16 @ B^T (fp16 MFMA, split-K=8)
// grid (64 m-tiles, 8 k-splits), 256 threads = 4 waves; barrier-free K-loop
__global__ __launch_bounds__(256) void k_bgemm(const float* __restrict__ Bw, float* ws)
{
    int m0 = blockIdx.x * 64;
    int ks = blockIdx.y * 512;
    const ushort* U16 = (const ushort*)(ws + OU);
    float* gP = ws + blockIdx.y * 262144;            // partials over dead projection region
    __shared__ __align__(16) ushort sB[64 * 512];    // [64 q][512 k] fp16, XOR-swizzled, 64KB
    int t = threadIdx.x;
    int lane = t & 63, w = t >> 6;

    // stage B k-slice, fp32 -> fp16, swizzled: thread t -> row q=t>>2, k-range (t&3)*128
    {
        int q = t >> 2, kc = (t & 3) * 128;
        const float* src = Bw + q * 4096 + ks + kc;
        char* base = (char*)sB + q * 1024;
        #pragma unroll
        for (int g2 = 0; g2 < 16; ++g2) {            // one 16B chunk (8 fp16) per iter
            float4 a4 = *(const float4*)&src[g2 * 8];
            float4 b4 = *(const float4*)&src[g2 * 8 + 4];
            union { _Float16 f[8]; f16x8 v; } pk;
            pk.f[0] = (_Float16)a4.x; pk.f[1] = (_Float16)a4.y;
            pk.f[2] = (_Float16)a4.z; pk.f[3] = (_Float16)a4.w;
            pk.f[4] = (_Float16)b4.x; pk.f[5] = (_Float16)b4.y;
            pk.f[6] = (_Float16)b4.z; pk.f[7] = (_Float16)b4.w;
            int c = (kc >> 3) + g2;                  // chunk index 0..63
            *(f16x8*)(base + ((c ^ (q & 7)) * 16)) = pk.v;
        }
    }
    __syncthreads();

    int lr = lane & 15, lg = lane >> 4;
    int mrow = m0 + w * 16 + lr;
    const ushort* urow = U16 + (size_t)mrow * 4096 + ks + lg * 8;
    f32x4 acc[4] = {};
    #pragma unroll
    for (int kt = 0; kt < 16; ++kt) {
        f16x8 aU = *(const f16x8*)(urow + kt * 32);  // global direct (4 lanes = 64B line)
        int c = kt * 4 + lg;
        #pragma unroll
        for (int nt = 0; nt < 4; ++nt) {
            int q = nt * 16 + lr;
            f16x8 bB = *(const f16x8*)((const char*)sB + q * 1024 + ((c ^ (q & 7)) * 16));
            acc[nt] = __builtin_amdgcn_mfma_f32_16x16x32_f16(aU, bB, acc[nt], 0, 0, 0);
        }
    }
    // D: col=lane&15 -> q within tile, row=lg*4+reg -> m within 16
    #pragma unroll
    for (int nt = 0; nt < 4; ++nt) {
        #pragma unroll
        for (int reg = 0; reg < 4; ++reg) {
            int m = m0 + w * 16 + lg * 4 + reg;
            gP[m * 64 + nt * 16 + lr] = acc[nt][reg];
        }
    }
}

// ---------------------------------------------------------------- K5: reduce 8 partials + scatter to [B,S,D]
__global__ __launch_bounds__(256) void k_reduce(const float* __restrict__ ws, float* __restrict__ out)
{
    int e0 = (blockIdx.x * 256 + threadIdx.x) * 4;      // 262144 total
    float4 s = *(const float4*)&ws[e0];
    #pragma unroll
    for (int sp = 1; sp < 8; ++sp) {
        float4 v = *(const float4*)&ws[sp * 262144 + e0];
        s.x += v.x; s.y += v.y; s.z += v.z; s.w += v.w;
    }
    int m = e0 >> 6, q0 = e0 & 63;
    int a = m >> 7, i = m & 127;
    int b_ = a >> 3, h = a & 7;
    *(float4*)&out[b_ * 65536 + i * 512 + h * 64 + q0] = s;
}

// ---------------------------------------------------------------- launch
extern "C" void kernel_launch(void* const* d_in, const int* in_sizes, int n_in,
                              void* d_out, int out_size, void* d_ws, size_t ws_size,
                              hipStream_t stream)
{
    const float* x   = (const float*)d_in[0];
    const float* y   = (const float*)d_in[1];
    const float* z   = (const float*)d_in[2];
    const float* Bw  = (const float*)d_in[3];
    const float* Wq  = (const float*)d_in[4];
    const float* bq  = (const float*)d_in[5];
    const float* Wk1 = (const float*)d_in[6];
    const float* bk1 = (const float*)d_in[7];
    const float* Wk2 = (const float*)d_in[8];
    const float* bk2 = (const float*)d_in[9];
    const float* Wv1 = (const float*)d_in[10];
    const float* bv1 = (const float*)d_in[11];
    const float* Wv2 = (const float*)d_in[12];
    const float* bv2 = (const float*)d_in[13];
    float* ws = (float*)d_ws;
    float* out = (float*)d_out;

    k_proj<<<dim3(8, 8, 5), 256, 0, stream>>>(x, y, z, Wq, bq, Wk1, bk1, Wk2, bk2,
                                              Wv1, bv1, Wv2, bv2, ws);
    k_dots<<<dim3(32, 3), 256, 0, stream>>>(ws);
    k_main<<<dim3(128, 32), 256, 0, stream>>>(ws);
    k_bgemm<<<dim3(64, 8), 256, 0, stream>>>(Bw, ws);
    k_reduce<<<256, 256, 0, stream>>>(ws, out);
}